// Round 6
// baseline (129.659 us; speedup 1.0000x reference)
//
#include <hip/hip_runtime.h>

#define N_TOTAL 32768
#define D_DIM   512
#define C_DIM   64
#define K_DIM   16
#define M_DIM   128
#define NODES_  15
#define ROWS    32   // rows per block in fused kernel

typedef unsigned short u16;
typedef unsigned int   u32;
typedef float f32x4 __attribute__((ext_vector_type(4)));
typedef unsigned int u32x4 __attribute__((ext_vector_type(4)));

__device__ __forceinline__ u32 f2bf_bits(float f) {
    u32 u = __float_as_uint(f);
    return (u + 0x7FFFu + ((u >> 16) & 1u)) >> 16;   // RNE
}
__device__ __forceinline__ float bf_lo(u32 u) { return __uint_as_float(u << 16); }
__device__ __forceinline__ float bf_hi(u32 u) { return __uint_as_float(u & 0xFFFF0000u); }

// ---------------------------------------------------------------------------
// Kernel 1: pair-merged LUT. LUT2[p][kk][m] (bf16), p=0..31, kk=k0|(k1<<4):
//   LUT2[p][kk][m] = L[m][(2p)*16+k0] + L[m][(2p+1)*16+k1]
// 32*256*128 bf16 = 2 MB (L2-resident). L is 512 KB.
// ---------------------------------------------------------------------------
__global__ __launch_bounds__(256) void build_lut_kernel(
    const float* __restrict__ L, u16* __restrict__ LUT)
{
    int idx = blockIdx.x * 256 + threadIdx.x;   // 131072 threads
    int q  = idx & 15;                          // col-group (8 cols)
    int kk = (idx >> 4) & 255;
    int p  = idx >> 12;                         // 0..31
    int c0 = (2 * p) * 16 + (kk & 15);
    int c1 = (2 * p + 1) * 16 + (kk >> 4);
    u32x4 w;
    #pragma unroll
    for (int h = 0; h < 4; ++h) {
        int m0 = q * 8 + 2 * h;
        float a0 = L[m0 * 1024 + c0]       + L[m0 * 1024 + c1];
        float a1 = L[(m0 + 1) * 1024 + c0] + L[(m0 + 1) * 1024 + c1];
        w[h] = f2bf_bits(a0) | (f2bf_bits(a1) << 16);
    }
    *(u32x4*)(LUT + (size_t)((p << 8) | kk) * M_DIM + q * 8) = w;
}

// ---------------------------------------------------------------------------
// Kernel 2 (fused), 32 rows/block:
//   phase 1: depth-4 tree descent per (row, class), direct global gathers on I
//            (one wave per row-iteration; gathers stay in that row's 32 lines);
//   phase 2: out[n,m] = sum_p LUT2[p][kk(n,p)][m]; each thread owns 2 rows x
//            8 cols -> 64 independent 16-B L2 loads (high MLP). Out stores are
//            nontemporal: never reused, keeps the 2 MB LUT L2-resident.
// Forward of the STE reference: sign(h) drives a binary descent; argmax leaf
// == descent leaf (any other leaf scores <= 2 < 4). h==0 -> bit 0 == argmax
// first-max tie rule.
// ---------------------------------------------------------------------------
__global__ __launch_bounds__(256) void fused_kernel(
    const float* __restrict__ I,
    const float* __restrict__ T,
    const int* __restrict__ dims,
    const u16* __restrict__ LUT,
    float* __restrict__ out)
{
    __shared__ float sT[C_DIM * NODES_];    // 3.75 KB
    __shared__ int   sDims[C_DIM * 4];      // 1 KB
    __shared__ int   sCode[ROWS * 65];      // 8.3 KB, pad stride 65

    const int tid = threadIdx.x;
    const int n0  = blockIdx.x * ROWS;

    sDims[tid] = dims[tid];
    for (int j = tid; j < C_DIM * NODES_; j += 256) sT[j] = T[j];
    __syncthreads();

    // ---- phase 1: codes. 2048 descents, 8 per thread (independent chains). ----
    #pragma unroll
    for (int it = 0; it < (ROWS * C_DIM) / 256; ++it) {
        int t   = it * 256 + tid;
        int row = t >> 6;
        int c   = t & 63;
        const float* v = I + (size_t)(n0 + row) * D_DIM;
        int node = 0, k = 0;
        #pragma unroll
        for (int l = 0; l < 4; ++l) {
            float h = v[sDims[(c << 2) + l]] - sT[c * NODES_ + node];
            int bit = (h > 0.0f) ? 1 : 0;
            k = (k << 1) | bit;
            node = (node << 1) + 1 + bit;
        }
        sCode[row * 65 + c] = k;
    }
    __syncthreads();

    // ---- phase 2: accumulate. Thread = (rows r & r+16, cols q*8..q*8+7). ----
    const int r = tid >> 4;      // 0..15
    const int q = tid & 15;      // 0..15
    const int* codeA = sCode + r * 65;
    const int* codeB = sCode + (r + 16) * 65;

    f32x4 a0 = (f32x4)0.f, a1 = (f32x4)0.f;
    f32x4 b0 = (f32x4)0.f, b1 = (f32x4)0.f;

    #pragma unroll
    for (int p = 0; p < 32; ++p) {
        u32 kkA = (u32)codeA[2 * p] | ((u32)codeA[2 * p + 1] << 4);  // LDS broadcast
        u32 kkB = (u32)codeB[2 * p] | ((u32)codeB[2 * p + 1] << 4);
        const u32x4 va = *(const u32x4*)(LUT + (size_t)(((p << 8) | kkA) << 7) + (q << 3));
        const u32x4 vb = *(const u32x4*)(LUT + (size_t)(((p << 8) | kkB) << 7) + (q << 3));
        a0.x += bf_lo(va.x); a0.y += bf_hi(va.x);
        a0.z += bf_lo(va.y); a0.w += bf_hi(va.y);
        a1.x += bf_lo(va.z); a1.y += bf_hi(va.z);
        a1.z += bf_lo(va.w); a1.w += bf_hi(va.w);
        b0.x += bf_lo(vb.x); b0.y += bf_hi(vb.x);
        b0.z += bf_lo(vb.y); b0.w += bf_hi(vb.y);
        b1.x += bf_lo(vb.z); b1.y += bf_hi(vb.z);
        b1.z += bf_lo(vb.w); b1.w += bf_hi(vb.w);
    }

    f32x4* oA = (f32x4*)(out + (size_t)(n0 + r) * M_DIM + (q << 3));
    f32x4* oB = (f32x4*)(out + (size_t)(n0 + r + 16) * M_DIM + (q << 3));
    __builtin_nontemporal_store(a0, oA);
    __builtin_nontemporal_store(a1, oA + 1);
    __builtin_nontemporal_store(b0, oB);
    __builtin_nontemporal_store(b1, oB + 1);
}

extern "C" void kernel_launch(void* const* d_in, const int* in_sizes, int n_in,
                              void* d_out, int out_size, void* d_ws, size_t ws_size,
                              hipStream_t stream) {
    // inputs: I(0) T(1) L(2) S(3) B(4) dims(5) temp(6) — fp32, dims int32
    const float* I    = (const float*)d_in[0];
    const float* T    = (const float*)d_in[1];
    const float* L    = (const float*)d_in[2];
    const int*   dims = (const int*)d_in[5];

    u16* LUT = (u16*)d_ws;                                 // 2 MB scratch

    hipLaunchKernelGGL(build_lut_kernel, dim3(512), dim3(256), 0, stream, L, LUT);
    hipLaunchKernelGGL(fused_kernel, dim3(N_TOTAL / ROWS), dim3(256), 0, stream,
                       I, T, dims, LUT, (float*)d_out);
}

// Round 7
// 127.895 us; speedup vs baseline: 1.0138x; 1.0138x over previous
//
#include <hip/hip_runtime.h>

#define N_TOTAL 32768
#define D_DIM   512
#define C_DIM   64
#define K_DIM   16
#define M_DIM   128
#define NODES_  15
#define ROWS    16   // rows per block in fused kernel (16 = best measured, r4)

typedef unsigned short u16;
typedef unsigned int   u32;
typedef float f32x4 __attribute__((ext_vector_type(4)));
typedef unsigned int u32x4 __attribute__((ext_vector_type(4)));

__device__ __forceinline__ u32 f2bf_bits(float f) {
    u32 u = __float_as_uint(f);
    return (u + 0x7FFFu + ((u >> 16) & 1u)) >> 16;   // RNE
}
__device__ __forceinline__ float bf_lo(u32 u) { return __uint_as_float(u << 16); }
__device__ __forceinline__ float bf_hi(u32 u) { return __uint_as_float(u & 0xFFFF0000u); }

// ---------------------------------------------------------------------------
// Kernel 1: pair-merged LUT. LUT2[p][kk][m] (bf16), p=0..31, kk=k0|(k1<<4):
//   LUT2[p][kk][m] = L[m][(2p)*16+k0] + L[m][(2p+1)*16+k1]
// 32*256*128 bf16 = 2 MB (L2-resident). L is 512 KB.
// ---------------------------------------------------------------------------
__global__ __launch_bounds__(256) void build_lut_kernel(
    const float* __restrict__ L, u16* __restrict__ LUT)
{
    int idx = blockIdx.x * 256 + threadIdx.x;   // 131072 threads
    int q  = idx & 15;                          // col-group (8 cols)
    int kk = (idx >> 4) & 255;
    int p  = idx >> 12;                         // 0..31
    int c0 = (2 * p) * 16 + (kk & 15);
    int c1 = (2 * p + 1) * 16 + (kk >> 4);
    u32x4 w;
    #pragma unroll
    for (int h = 0; h < 4; ++h) {
        int m0 = q * 8 + 2 * h;
        float a0 = L[m0 * 1024 + c0]       + L[m0 * 1024 + c1];
        float a1 = L[(m0 + 1) * 1024 + c0] + L[(m0 + 1) * 1024 + c1];
        w[h] = f2bf_bits(a0) | (f2bf_bits(a1) << 16);
    }
    *(u32x4*)(LUT + (size_t)((p << 8) | kk) * M_DIM + q * 8) = w;
}

// ---------------------------------------------------------------------------
// Kernel 2 (fused), 16 rows/block (2048 blocks):
//   phase 1: depth-4 tree descent per (row, class), direct global gathers on I
//            (4 independent chains/thread; each wave's gathers stay within its
//            row's 32 cache lines);
//   phase 2: out[n,m] = sum_p LUT2[p][kk(n,p)][m]; thread = (row, 8 cols) ->
//            32 independent 16-B L2 loads. Out stores nontemporal (write-once,
//            keeps the 2 MB LUT L2-resident).
// Forward of the STE reference: sign(h) drives a binary descent; argmax leaf
// == descent leaf (any other leaf scores <= 2 < 4). h==0 -> bit 0 == argmax
// first-max tie rule.
// ---------------------------------------------------------------------------
__global__ __launch_bounds__(256) void fused_kernel(
    const float* __restrict__ I,
    const float* __restrict__ T,
    const int* __restrict__ dims,
    const u16* __restrict__ LUT,
    float* __restrict__ out)
{
    __shared__ float sT[C_DIM * NODES_];    // 3.75 KB
    __shared__ int   sDims[C_DIM * 4];      // 1 KB
    __shared__ int   sCode[ROWS * 65];      // 4.1 KB, pad stride 65

    const int tid = threadIdx.x;
    const int n0  = blockIdx.x * ROWS;

    sDims[tid] = dims[tid];
    for (int j = tid; j < C_DIM * NODES_; j += 256) sT[j] = T[j];
    __syncthreads();

    // ---- phase 1: codes. 1024 descents, 4 per thread (independent chains). ----
    #pragma unroll
    for (int it = 0; it < (ROWS * C_DIM) / 256; ++it) {
        int t   = it * 256 + tid;
        int row = t >> 6;
        int c   = t & 63;
        const float* v = I + (size_t)(n0 + row) * D_DIM;
        int node = 0, k = 0;
        #pragma unroll
        for (int l = 0; l < 4; ++l) {
            float h = v[sDims[(c << 2) + l]] - sT[c * NODES_ + node];
            int bit = (h > 0.0f) ? 1 : 0;
            k = (k << 1) | bit;
            node = (node << 1) + 1 + bit;
        }
        sCode[row * 65 + c] = k;
    }
    __syncthreads();

    // ---- phase 2: accumulate. Thread = (row r, cols q*8..q*8+7). ----
    const int r = tid >> 4;      // 0..15
    const int q = tid & 15;      // 0..15
    const int* codeRow = sCode + r * 65;

    f32x4 a0 = (f32x4)0.f, a1 = (f32x4)0.f;

    #pragma unroll
    for (int p = 0; p < 32; ++p) {
        u32 kk = (u32)codeRow[2 * p] | ((u32)codeRow[2 * p + 1] << 4);  // LDS broadcast
        const u32x4 v = *(const u32x4*)(LUT + (size_t)(((p << 8) | kk) << 7) + (q << 3));
        a0.x += bf_lo(v.x); a0.y += bf_hi(v.x);
        a0.z += bf_lo(v.y); a0.w += bf_hi(v.y);
        a1.x += bf_lo(v.z); a1.y += bf_hi(v.z);
        a1.z += bf_lo(v.w); a1.w += bf_hi(v.w);
    }

    f32x4* o = (f32x4*)(out + (size_t)(n0 + r) * M_DIM + (q << 3));
    __builtin_nontemporal_store(a0, o);
    __builtin_nontemporal_store(a1, o + 1);
}

extern "C" void kernel_launch(void* const* d_in, const int* in_sizes, int n_in,
                              void* d_out, int out_size, void* d_ws, size_t ws_size,
                              hipStream_t stream) {
    // inputs: I(0) T(1) L(2) S(3) B(4) dims(5) temp(6) — fp32, dims int32
    const float* I    = (const float*)d_in[0];
    const float* T    = (const float*)d_in[1];
    const float* L    = (const float*)d_in[2];
    const int*   dims = (const int*)d_in[5];

    u16* LUT = (u16*)d_ws;                                 // 2 MB scratch

    hipLaunchKernelGGL(build_lut_kernel, dim3(512), dim3(256), 0, stream, L, LUT);
    hipLaunchKernelGGL(fused_kernel, dim3(N_TOTAL / ROWS), dim3(256), 0, stream,
                       I, T, dims, LUT, (float*)d_out);
}